// Round 1
// baseline (195.780 us; speedup 1.0000x reference)
//
#include <hip/hip_runtime.h>

// DenseLayerWithComplexNeurons: out = per-cell-type-MLP( x @ W^T + b )
// M = B*S = 8192, K = DIN = 1024, N = A*DOUT = 4096, DOUT = 1024
// T = 4 cell types, G = 256 neurons/type, A = 4, H = 8.
//
// Round 1: bf16 MFMA GEMM 128x128/BK64, fused LDS epilogue. 154.5 us.
// Round 2: XOR-swizzled staging -> 0 conflicts, 118.9 us.
// Round 3: 256x128 block, 128x64 wave tiles, 32x32x16 MFMA. 101.6 us.
//   PMC: MfmaUtil 29%, VALUBusy 35% -> 2-barrier structure ceiling (~676 TF),
//   every pipe (MFMA 27.5us, LDS 30us, L2 23us) individually ~30us.
// Round 4: 256x256 block, 8 waves, 4-phase/K-tile pipeline (T3+T4+T5):
//   raw s_barrier (no vmcnt(0) drain in loop), counted s_waitcnt vmcnt(2),
//   128 KiB double-buffered LDS, unit staging 4-6 phases ahead, setprio
//   around MFMA clusters, next-tile A-mh0 register prefetch at p3.
//   Same verified swizzle + C-layout; epilogue rescaled to BN=256.

typedef __bf16 bf16x8 __attribute__((ext_vector_type(8)));
typedef float f32x4 __attribute__((ext_vector_type(4)));
typedef float f32x16 __attribute__((ext_vector_type(16)));

#define BM 256
#define BN 256
#define BK 64
#define KDIM 1024
#define NT 16                    // K / BK
#define BUFB 65536               // bytes per LDS buffer: A 32K | B 32K
#define BBASE 32768              // B tile offset within buffer
#define ZS 260                   // z slab stride (floats); 260%32=4 shifts rows
#define XN8 (8192 * 1024 / 8)
#define WN8 (4096 * 1024 / 8)

__global__ __launch_bounds__(256) void cvt_bf16_kernel(
    const float* __restrict__ x, const float* __restrict__ w,
    __bf16* __restrict__ xb, __bf16* __restrict__ wb) {
    int i = blockIdx.x * 256 + threadIdx.x;
    const float* src;
    __bf16* dst;
    int j;
    if (i < XN8) { src = x; dst = xb; j = i; }
    else         { src = w; dst = wb; j = i - XN8; }
    const f32x4* p = (const f32x4*)src + 2 * (size_t)j;
    f32x4 a = p[0], b = p[1];
    bf16x8 o;
    o[0] = (__bf16)a[0]; o[1] = (__bf16)a[1]; o[2] = (__bf16)a[2]; o[3] = (__bf16)a[3];
    o[4] = (__bf16)b[0]; o[5] = (__bf16)b[1]; o[6] = (__bf16)b[2]; o[7] = (__bf16)b[3];
    ((bf16x8*)dst)[j] = o;
}

union __align__(16) SmemU {
    unsigned char raw[2 * BUFB];   // 131072 B: two {A|B} K-tile buffers
    float z[64 * ZS];              // 66560 B epilogue slab (reuses staging LDS)
};

#define FENCE() asm volatile("" ::: "memory")
#define BARRIER() do { FENCE(); __builtin_amdgcn_s_barrier(); FENCE(); } while (0)

__global__ __launch_bounds__(512, 2) void fused_gemm_mlp_kernel(
    const __bf16* __restrict__ Ag,   // [8192][1024] bf16 (x)
    const __bf16* __restrict__ Bg,   // [4096][1024] bf16 (weight, B^T layout)
    const float* __restrict__ bias,  // [4096]
    const float* __restrict__ cw1,   // [4][4][8]
    const float* __restrict__ cb1,   // [4][8]
    const float* __restrict__ cw2,   // [4][8]
    const float* __restrict__ cb2,   // [4]
    float* __restrict__ out)         // [8192][1024]
{
    __shared__ SmemU u;

    const int tid  = threadIdx.x;
    const int wave = tid >> 6;
    const int lane = tid & 63;
    const int wm = wave >> 2;        // row half (0..1): 128 rows each
    const int wn = wave & 3;         // col quarter (0..3): 64 cols each
    const int bn0 = blockIdx.x * BN; // n offset in [0,4096)
    const int bm0 = blockIdx.y * BM; // m offset in [0,8192)

    // ---- staging lane mapping (XOR swizzle per 8-row/1KB chunk; as R2/R3) ----
    const int srow  = lane >> 3;
    const int scol8 = (((lane & 7) ^ srow) * 8);

    // ---- fragment LDS offsets (bytes, buffer-relative) ----
    const int lr5 = lane & 31;
    const int lk2 = lane >> 5;   // 0..1
    const int lx  = lane & 7;
    const int lg  = lr5 >> 3;    // 0..3
    int aoff[4], boff[2], slot[4];
#pragma unroll
    for (int mi = 0; mi < 4; ++mi) aoff[mi] = (wm * 16 + mi * 4 + lg) * 1024 + lx * 128;
#pragma unroll
    for (int ni = 0; ni < 2; ++ni) boff[ni] = BBASE + (wn * 8 + ni * 4 + lg) * 1024 + lx * 128;
#pragma unroll
    for (int ks = 0; ks < 4; ++ks) slot[ks] = ((ks * 2 + lk2) ^ lx) * 16;

    const char* sb = (const char*)u.raw;

    // one unit = 128 rows x 64 k = 16 chunks of 1KB; each wave stages 2 chunks
    auto stageA = [&](int t, int half) {
        if (t >= NT) return;
        const int dst = (t & 1) * BUFB + (half * 16 + wave * 2) * 1024;
        const __bf16* g = Ag + (size_t)(bm0 + half * 128 + wave * 16 + srow) * KDIM
                        + t * BK + scol8;
        __builtin_amdgcn_global_load_lds(
            (__attribute__((address_space(1))) void*)g,
            (__attribute__((address_space(3))) void*)&u.raw[dst], 16, 0, 0);
        __builtin_amdgcn_global_load_lds(
            (__attribute__((address_space(1))) void*)(g + 8 * KDIM),
            (__attribute__((address_space(3))) void*)&u.raw[dst + 1024], 16, 0, 0);
    };
    auto stageB = [&](int t, int half) {
        if (t >= NT) return;
        const int dst = (t & 1) * BUFB + BBASE + (half * 16 + wave * 2) * 1024;
        const __bf16* g = Bg + (size_t)(bn0 + half * 128 + wave * 16 + srow) * KDIM
                        + t * BK + scol8;
        __builtin_amdgcn_global_load_lds(
            (__attribute__((address_space(1))) void*)g,
            (__attribute__((address_space(3))) void*)&u.raw[dst], 16, 0, 0);
        __builtin_amdgcn_global_load_lds(
            (__attribute__((address_space(1))) void*)(g + 8 * KDIM),
            (__attribute__((address_space(3))) void*)&u.raw[dst + 1024], 16, 0, 0);
    };

    f32x16 acc[4][2] = {};           // 4 m-tiles x 2 n-tiles of 32x32 per wave
    bf16x8 aA[8];                    // A-mh0 frags (mi 0..1 x ks 0..3), prefetched
    bf16x8 a1f[8];                   // A-mh1 frags (mi 2..3)
    bf16x8 bf0[4], bf1[4];           // B ni0 / ni1 frags

    // ---- prologue: steady-state stage order B0(0) B1(0) A0(0) A1(0) B0(1) ----
    stageB(0, 0); stageB(0, 1); stageA(0, 0); stageA(0, 1); stageB(1, 0);
    asm volatile("s_waitcnt vmcnt(2)" ::: "memory");   // tile 0 fully landed
    BARRIER();
    // "p3(-1)": prefetch A-mh0(0), stage B1(1)
#pragma unroll
    for (int mi = 0; mi < 2; ++mi)
#pragma unroll
        for (int ks = 0; ks < 4; ++ks)
            aA[mi * 4 + ks] = *(const bf16x8*)(sb + aoff[mi] + slot[ks]);
    stageB(1, 1);

#pragma unroll 2
    for (int T = 0; T < NT; ++T) {
        const int buf  = (T & 1) * BUFB;
        const int nbuf = buf ^ BUFB;

        // ---- phase 0: read B-ni0 | stage A0(T+1) | MFMA Q(mh0,ni0) ----
        BARRIER();
#pragma unroll
        for (int ks = 0; ks < 4; ++ks)
            bf0[ks] = *(const bf16x8*)(sb + buf + boff[0] + slot[ks]);
        stageA(T + 1, 0);
        __builtin_amdgcn_s_setprio(1);
#pragma unroll
        for (int mi = 0; mi < 2; ++mi)
#pragma unroll
            for (int ks = 0; ks < 4; ++ks)
                acc[mi][0] = __builtin_amdgcn_mfma_f32_32x32x16_bf16(
                    aA[mi * 4 + ks], bf0[ks], acc[mi][0], 0, 0, 0);
        __builtin_amdgcn_s_setprio(0);

        // ---- phase 1: read B-ni1 | stage A1(T+1) | MFMA Q(mh0,ni1) ----
        BARRIER();
#pragma unroll
        for (int ks = 0; ks < 4; ++ks)
            bf1[ks] = *(const bf16x8*)(sb + buf + boff[1] + slot[ks]);
        stageA(T + 1, 1);
        __builtin_amdgcn_s_setprio(1);
#pragma unroll
        for (int mi = 0; mi < 2; ++mi)
#pragma unroll
            for (int ks = 0; ks < 4; ++ks)
                acc[mi][1] = __builtin_amdgcn_mfma_f32_32x32x16_bf16(
                    aA[mi * 4 + ks], bf1[ks], acc[mi][1], 0, 0, 0);
        __builtin_amdgcn_s_setprio(0);

        // ---- phase 2: read A-mh1 | stage B0(T+2) | MFMA Q(mh1,ni0) ----
        BARRIER();
#pragma unroll
        for (int mi = 0; mi < 2; ++mi)
#pragma unroll
            for (int ks = 0; ks < 4; ++ks)
                a1f[mi * 4 + ks] = *(const bf16x8*)(sb + buf + aoff[2 + mi] + slot[ks]);
        stageB(T + 2, 0);
        __builtin_amdgcn_s_setprio(1);
#pragma unroll
        for (int mi = 0; mi < 2; ++mi)
#pragma unroll
            for (int ks = 0; ks < 4; ++ks)
                acc[2 + mi][0] = __builtin_amdgcn_mfma_f32_32x32x16_bf16(
                    a1f[mi * 4 + ks], bf0[ks], acc[2 + mi][0], 0, 0, 0);
        __builtin_amdgcn_s_setprio(0);
        // counted drain, once per K-tile: leaves only B0(T+2) in flight;
        // guarantees A0/A1(T+1) + B0/B1(T+1) landed for the next 4 phases.
        asm volatile("s_waitcnt vmcnt(2)" ::: "memory");

        // ---- phase 3: prefetch A-mh0(T+1) | stage B1(T+2) | MFMA Q(mh1,ni1) ----
        BARRIER();
        if (T + 1 < NT) {
#pragma unroll
            for (int mi = 0; mi < 2; ++mi)
#pragma unroll
                for (int ks = 0; ks < 4; ++ks)
                    aA[mi * 4 + ks] = *(const bf16x8*)(sb + nbuf + aoff[mi] + slot[ks]);
        }
        stageB(T + 2, 1);
        __builtin_amdgcn_s_setprio(1);
#pragma unroll
        for (int mi = 0; mi < 2; ++mi)
#pragma unroll
            for (int ks = 0; ks < 4; ++ks)
                acc[2 + mi][1] = __builtin_amdgcn_mfma_f32_32x32x16_bf16(
                    a1f[mi * 4 + ks], bf1[ks], acc[2 + mi][1], 0, 0, 0);
        __builtin_amdgcn_s_setprio(0);
    }

    // ---- epilogue: per-neuron MLP over A=4 adjacent z columns ----
    const int tct = bn0 >> 10;  // cell type, block-uniform
    float w1[32], b1[8], w2[8];
#pragma unroll
    for (int i = 0; i < 32; ++i) w1[i] = cw1[tct * 32 + i];
#pragma unroll
    for (int i = 0; i < 8; ++i) { b1[i] = cb1[tct * 8 + i]; w2[i] = cw2[tct * 8 + i]; }
    const float b2 = cb2[tct];

    float bcol[2];
#pragma unroll
    for (int ni = 0; ni < 2; ++ni)
        bcol[ni] = bias[bn0 + wn * 64 + ni * 32 + lr5];

    const float L2E2 = 2.885390081777927f;  // 2*log2(e)

    asm volatile("s_waitcnt vmcnt(0)" ::: "memory");
    __syncthreads();  // all LDS reads/DMA done; safe to reuse as z slab

#pragma unroll
    for (int h = 0; h < 4; ++h) {  // 64-row slabs
        if (wm == (h >> 1)) {
            const int mi0 = (h & 1) * 2;
#pragma unroll
            for (int dmi = 0; dmi < 2; ++dmi) {
#pragma unroll
                for (int ni = 0; ni < 2; ++ni) {
                    const int n = wn * 64 + ni * 32 + lr5;
#pragma unroll
                    for (int g = 0; g < 4; ++g) {
                        // C/D 32x32 layout: col=lane&31, row=(reg&3)+8*(reg>>2)+4*(lane>>5)
                        const int rb = dmi * 32 + g * 8 + lk2 * 4;
                        u.z[(rb + 0) * ZS + n] = acc[mi0 + dmi][ni][g * 4 + 0] + bcol[ni];
                        u.z[(rb + 1) * ZS + n] = acc[mi0 + dmi][ni][g * 4 + 1] + bcol[ni];
                        u.z[(rb + 2) * ZS + n] = acc[mi0 + dmi][ni][g * 4 + 2] + bcol[ni];
                        u.z[(rb + 3) * ZS + n] = acc[mi0 + dmi][ni][g * 4 + 3] + bcol[ni];
                    }
                }
            }
        }
        __syncthreads();

        // 64 rows x 64 neurons = 4096 outputs; 8 per thread
#pragma unroll
        for (int it = 0; it < 8; ++it) {
            const int i = tid + it * 512;
            const int q = i & 63;       // neuron within block
            const int r = i >> 6;       // row within slab
            f32x4 z4 = *(const f32x4*)&u.z[r * ZS + 4 * q];
            float o = 0.f;
#pragma unroll
            for (int hh = 0; hh < 8; ++hh) {
                float pre = z4[0] * w1[0 * 8 + hh] + z4[1] * w1[1 * 8 + hh]
                          + z4[2] * w1[2 * 8 + hh] + z4[3] * w1[3 * 8 + hh] + b1[hh];
                float e = __builtin_amdgcn_exp2f(pre * L2E2);        // e^(2*pre)
                float th = 1.0f - 2.0f * __builtin_amdgcn_rcpf(e + 1.0f);
                o += th * w2[hh];
            }
            o += b2;
            out[(size_t)(bm0 + h * 64 + r) * 1024 + (bn0 >> 2) + q] = o;
        }
        __syncthreads();
    }
}

extern "C" void kernel_launch(void* const* d_in, const int* in_sizes, int n_in,
                              void* d_out, int out_size, void* d_ws, size_t ws_size,
                              hipStream_t stream) {
    const float* x    = (const float*)d_in[0];
    const float* w    = (const float*)d_in[1];
    const float* bias = (const float*)d_in[2];
    const float* cw1  = (const float*)d_in[3];
    const float* cb1  = (const float*)d_in[4];
    const float* cw2  = (const float*)d_in[5];
    const float* cb2  = (const float*)d_in[6];
    float* out = (float*)d_out;

    __bf16* xb = (__bf16*)d_ws;                       // 8192*1024 bf16 = 16 MB
    __bf16* wb = xb + (size_t)8192 * 1024;            // 4096*1024 bf16 = 8 MB

    cvt_bf16_kernel<<<(XN8 + WN8) / 256, 256, 0, stream>>>(x, w, xb, wb);

    dim3 grid(4096 / BN, 8192 / BM);  // (16, 32)
    fused_gemm_mlp_kernel<<<grid, 512, 0, stream>>>(xb, wb, bias, cw1, cb1, cw2, cb2, out);
}